// Round 6
// baseline (2606.336 us; speedup 1.0000x reference)
//
#include <hip/hip_runtime.h>
#include <cmath>

// CustomRNNCell: h_{t+1} = tanh(h_t @ W_h^T + b_h + x_t @ W_x^T + b_x)
// B=64, T=512, H=I=1024. Output: h_final [64,1024] fp32.
//
// R10: ONE fused kernel, two roles, overlapped:
//  - blocks 0..63   : scan role. R6 protocol VERBATIM (best measured, 1410us):
//      4 waves = 4 batch groups sharing one 32KB W_h slice (16 j-cols) in LDS,
//      flag-gated 2-slot bf16 ring, drain->flag->poll->pull per step.
//      Extra: gate on xp chunk counter once every 64 steps.
//  - blocks 64..8255: gemm role. Validated 64x64 xp tile, reindexed
//      chunk-major over t (chunk = 64 timesteps). xp stored via relaxed
//      AGENT-scope atomic stores (write-through -> visible cross-XCD, same
//      mechanism as the proven ring), then vmcnt(0) + one atomicAdd on the
//      chunk counter. Scan first-touches xp lines only after the gate.
//  Overlap: scan consumes ~2.75us/step; gemm produces a 64-t chunk in
//  ~50-90us << scan's 176us/chunk -> gemm stays ahead after chunk 0.
//  No deadlock: gemm depends on nothing; scan blocks occupy 64 CUs leaving
//  plenty of capacity for gemm blocks to stream through.

#define Bsz 64
#define Tsz 512
#define Hsz 1024

typedef float  f32x4 __attribute__((ext_vector_type(4)));
typedef short  s16x8 __attribute__((ext_vector_type(8)));

__device__ __forceinline__ unsigned short f2bf(float f) {
  unsigned u = __float_as_uint(f);
  u += 0x7fff + ((u >> 16) & 1);   // round-to-nearest-even (finite inputs)
  return (unsigned short)(u >> 16);
}

__device__ __forceinline__ void pack8(unsigned short* d, float4 v0, float4 v1) {
  d[0] = f2bf(v0.x); d[1] = f2bf(v0.y); d[2] = f2bf(v0.z); d[3] = f2bf(v0.w);
  d[4] = f2bf(v1.x); d[5] = f2bf(v1.y); d[6] = f2bf(v1.z); d[7] = f2bf(v1.w);
}

__device__ __forceinline__ float fast_tanh(float x) {
  float e = __expf(2.0f * x);
  return 1.0f - 2.0f / (e + 1.0f);
}

// Ring (bf16 units): slot[2] x group[4] x [(k>>3)*128 + b*8 + (k&7)].
// Slot stride 16384 u64 (128 KB), group stride 4096 u64 (32 KB).
// Consumer frag kk, lane(m,q): u64 idx kk*128 + q*32 + m*2 (+1).
// Producer (gb,gj), lane(m,q): u64 idx (gj*2+(q>>1))*32 + m*2 + (q&1),
// hv[0..3] packed low->high.   [all R6-validated]

__global__ __launch_bounds__(256, 1) void fused_kernel(
    const float* __restrict__ x,  const float* __restrict__ Wh,
    const float* __restrict__ bh, const float* __restrict__ Wx,
    const float* __restrict__ bx,
    float* __restrict__ xp, float* __restrict__ out,
    unsigned long long* __restrict__ ring, unsigned* __restrict__ flags,
    unsigned* __restrict__ cnt) {
  __shared__ unsigned short Al[64 * 32];
  __shared__ unsigned short Bl[64 * 32];
  __shared__ unsigned short Wl[16 * 1024];   // scan role: 32 KB W_h slice

  const int tid  = threadIdx.x;
  const int w    = tid >> 6;
  const int lane = tid & 63;
  const int m    = lane & 15;
  const int q    = lane >> 4;

  if (blockIdx.x >= 64) {
    // ================= gemm role (validated body, chunk-major) =============
    const int g   = blockIdx.x - 64;
    const int c   = g >> 10;          // t-chunk 0..7 (64 timesteps each)
    const int b   = (g >> 4) & 63;    // batch row
    const int ct  = g & 15;           // col tile
    const int row0 = b * 512 + c * 64;
    const int col0 = ct * 64;

    f32x4 acc[4];
#pragma unroll
    for (int i = 0; i < 4; ++i) acc[i] = (f32x4){0.f, 0.f, 0.f, 0.f};

    const int sr = tid >> 2;
    const int sc = tid & 3;
    const int sw = sc ^ ((sr >> 1) & 3);

    for (int kt = 0; kt < 32; ++kt) {
      const int k0 = kt * 32 + sc * 8;
      {
        const float* p = x + (size_t)(row0 + sr) * 1024 + k0;
        pack8(&Al[sr * 32 + sw * 8], *(const float4*)p, *(const float4*)(p + 4));
      }
      {
        const float* p = Wx + (size_t)(col0 + sr) * 1024 + k0;
        pack8(&Bl[sr * 32 + sw * 8], *(const float4*)p, *(const float4*)(p + 4));
      }
      __syncthreads();
      const int arow = w * 16 + m;
      s16x8 a = *(const s16x8*)&Al[arow * 32 + ((q ^ ((arow >> 1) & 3)) << 3)];
#pragma unroll
      for (int nt = 0; nt < 4; ++nt) {
        const int nrow = nt * 16 + m;
        s16x8 bb = *(const s16x8*)&Bl[nrow * 32 + ((q ^ ((nrow >> 1) & 3)) << 3)];
        acc[nt] = __builtin_amdgcn_mfma_f32_16x16x32_bf16(a, bb, acc[nt], 0, 0, 0);
      }
      __syncthreads();
    }

#pragma unroll
    for (int nt = 0; nt < 4; ++nt) {
      const int col  = col0 + nt * 16 + m;
      const float bias = bx[col] + bh[col];
#pragma unroll
      for (int r = 0; r < 4; ++r) {
        const int rowg = row0 + w * 16 + q * 4 + r;  // = b*512 + t
        const int bb = rowg >> 9;
        const int tt = rowg & 511;
        // write-through (agent scope) so scan blocks on other XCDs see it
        unsigned* px = (unsigned*)&xp[(size_t)tt * (Bsz * Hsz) + bb * Hsz + col];
        __hip_atomic_store(px, __float_as_uint(acc[nt][r] + bias),
                           __ATOMIC_RELAXED, __HIP_MEMORY_SCOPE_AGENT);
      }
    }
    // drain stores, then bump the chunk counter once per block
    asm volatile("s_waitcnt vmcnt(0)" ::: "memory");
    __syncthreads();
    if (tid == 0)
      __hip_atomic_fetch_add(&cnt[c], 1u, __ATOMIC_RELAXED,
                             __HIP_MEMORY_SCOPE_AGENT);
    return;
  }

  // ================= scan role (R6 verbatim, 4 groups share Wl) ============
  const int gb = w;                 // wave = batch group 0..3
  const int gj = blockIdx.x;        // 0..63 j-slice (16 output cols)
  const int j0 = gj * 16;
  const int rb = gb * 16;

  // W_h rows j0..j0+15 -> LDS bf16, chunk-swizzled (c ^= row&7); validated.
  for (int i = 0; i < 8; ++i) {
    const int jr  = i * 2 + (tid >> 7);
    const int cch = tid & 127;
    const float* p = Wh + (size_t)(j0 + jr) * 1024 + cch * 8;
    pack8(&Wl[jr * 1024 + ((cch ^ (jr & 7)) << 3)],
          *(const float4*)p, *(const float4*)(p + 4));
  }
  __syncthreads();
  __builtin_amdgcn_s_setprio(1);    // scan is the critical path

  unsigned* grpflags = flags + gb * 1024;          // 64 flags x 64-B stride
  unsigned* myflag   = grpflags + gj * 16;
  const unsigned* pollflag = grpflags + lane * 16; // lane l polls producer l

  unsigned long long* const grp = ring + (size_t)gb * 4096;
  const int cons_off = q * 32 + m * 2;
  const int prod_off = (gj * 2 + (q >> 1)) * 32 + m * 2 + (q & 1);
  const int jl = m;                                // local W row

  for (int t = 0; t < Tsz; ++t) {
    if ((t & 63) == 0) {
      // gate on xp chunk readiness (8 polls total across the whole scan)
      const unsigned ci = (unsigned)(t >> 6);
      unsigned cv = __hip_atomic_load(&cnt[ci], __ATOMIC_RELAXED,
                                      __HIP_MEMORY_SCOPE_AGENT);
      while (cv < 1024u) {
        __builtin_amdgcn_s_sleep(8);
        cv = __hip_atomic_load(&cnt[ci], __ATOMIC_RELAXED,
                               __HIP_MEMORY_SCOPE_AGENT);
      }
    }

    // xp_t for (b = rb+m, j = j0+q*4+r) — first-touch after the gate
    const float4 xv = *(const float4*)(
        xp + (size_t)t * (Bsz * Hsz) + (size_t)(rb + m) * Hsz + j0 + q * 4);
    const float* xf = (const float*)&xv;

    f32x4 acc0 = (f32x4){0.f, 0.f, 0.f, 0.f};
    f32x4 acc1 = (f32x4){0.f, 0.f, 0.f, 0.f};
    f32x4 acc2 = (f32x4){0.f, 0.f, 0.f, 0.f};
    f32x4 acc3 = (f32x4){0.f, 0.f, 0.f, 0.f};

    if (t > 0) {
      const unsigned tg = (unsigned)t;
      // Poll to full readiness: one flag per lane, wave-wide ballot.
      unsigned v = __hip_atomic_load(pollflag, __ATOMIC_RELAXED,
                                     __HIP_MEMORY_SCOPE_AGENT);
      while (!__all((int)(v >= tg))) {
        __builtin_amdgcn_s_sleep(1);
        v = __hip_atomic_load(pollflag, __ATOMIC_RELAXED,
                              __HIP_MEMORY_SCOPE_AGENT);
      }

      // Bulk-issue all data loads (contiguous u64 pairs per fragment).
      const unsigned long long* rbase =
          grp + (size_t)(t & 1) * 16384 + cons_off;
      unsigned long long d[64];
#pragma unroll
      for (int kk = 0; kk < 32; ++kk) {
        d[2 * kk]     = __hip_atomic_load(rbase + kk * 128,     __ATOMIC_RELAXED,
                                          __HIP_MEMORY_SCOPE_AGENT);
        d[2 * kk + 1] = __hip_atomic_load(rbase + kk * 128 + 1, __ATOMIC_RELAXED,
                                          __HIP_MEMORY_SCOPE_AGENT);
      }

#pragma unroll
      for (int kk = 0; kk < 32; ++kk) {
        union { unsigned long long u[2]; s16x8 v; } hb;
        hb.u[0] = d[2 * kk];
        hb.u[1] = d[2 * kk + 1];
        s16x8 wf = *(const s16x8*)&Wl[jl * 1024 + (((kk * 4 + q) ^ (jl & 7)) << 3)];
        f32x4& ac = ((kk & 3) == 0) ? acc0 : ((kk & 3) == 1) ? acc1
                   : ((kk & 3) == 2) ? acc2 : acc3;
        ac = __builtin_amdgcn_mfma_f32_16x16x32_bf16(wf, hb.v, ac, 0, 0, 0);
      }
    }

    const f32x4 accs = (acc0 + acc1) + (acc2 + acc3);
    float hv[4];
#pragma unroll
    for (int r = 0; r < 4; ++r) hv[r] = fast_tanh(accs[r] + xf[r]);

    if (t == Tsz - 1) {
      *(float4*)&out[(size_t)(rb + m) * Hsz + j0 + q * 4] =
          make_float4(hv[0], hv[1], hv[2], hv[3]);
    } else {
      const unsigned long long s =
          (unsigned long long)f2bf(hv[0])        |
          ((unsigned long long)f2bf(hv[1]) << 16) |
          ((unsigned long long)f2bf(hv[2]) << 32) |
          ((unsigned long long)f2bf(hv[3]) << 48);
      unsigned long long* wb = grp + (size_t)((t + 1) & 1) * 16384;
      __hip_atomic_store(wb + prod_off, s, __ATOMIC_RELAXED,
                         __HIP_MEMORY_SCOPE_AGENT);
      // Drain own store to the coherence point, then publish readiness.
      asm volatile("s_waitcnt vmcnt(0)" ::: "memory");
      if (lane == 0)
        __hip_atomic_store(myflag, (unsigned)(t + 1), __ATOMIC_RELAXED,
                           __HIP_MEMORY_SCOPE_AGENT);
    }
  }
}

extern "C" void kernel_launch(void* const* d_in, const int* in_sizes, int n_in,
                              void* d_out, int out_size, void* d_ws, size_t ws_size,
                              hipStream_t stream) {
  (void)in_sizes; (void)n_in; (void)out_size; (void)ws_size;
  const float* x  = (const float*)d_in[0];  // [64,512,1024]
  const float* Wh = (const float*)d_in[1];  // [1024,1024]
  const float* bh = (const float*)d_in[2];  // [1024]
  const float* Wx = (const float*)d_in[3];  // [1024,1024]
  const float* bx = (const float*)d_in[4];  // [1024]
  float* out = (float*)d_out;               // [64,1024]

  char* ws = (char*)d_ws;
  unsigned*           flags = (unsigned*)ws;                    // 16 KB
  unsigned*           cnt   = (unsigned*)(ws + 16384);          // 32 B
  unsigned long long* ring  = (unsigned long long*)(ws + 65536);// 256 KB
  float*              xp    = (float*)(ws + (1 << 20));         // 128 MB

  // zero flags + chunk counters (step 0 reads no h buffer)
  hipMemsetAsync(d_ws, 0, 32768, stream);

  // 64 scan blocks first (resident early), then 8192 gemm blocks chunk-major
  fused_kernel<<<dim3(64 + 8192), dim3(256), 0, stream>>>(
      x, Wh, bh, Wx, bx, xp, out, ring, flags, cnt);
}

// Round 8
// 2329.797 us; speedup vs baseline: 1.1187x; 1.1187x over previous
//
#include <hip/hip_runtime.h>
#include <cmath>

// CustomRNNCell: h_{t+1} = tanh(h_t @ W_h^T + b_h + x_t @ W_x^T + b_x)
// B=64, T=512, H=I=1024. Output: h_final [64,1024] fp32.
//
// R12 = R6 (best verified: scan 1410us) + GEMM de-fat:
//  - Phase 0: cvt pre-pass x->xb, Wx->Wxb (bf16). Conversion once per
//    element instead of 16x inside the col-tiled GEMM.
//  - Phase 1: xp GEMM with VALIDATED 64x64 tile/indexing, staging via plain
//    short8 copies from the bf16 sources (no per-iter cvt). Fallback to the
//    original fp32-staging GEMM if ws_size can't fit the bf16 copies.
//  - Phase 2: R6 scan VERBATIM except flags packed at stride 1 (poll gather
//    = 4 cache lines instead of 64; producer publish path unchanged).

#define Bsz 64
#define Tsz 512
#define Hsz 1024

typedef float  f32x4 __attribute__((ext_vector_type(4)));
typedef short  s16x8 __attribute__((ext_vector_type(8)));

__device__ __forceinline__ unsigned short f2bf(float f) {
  unsigned u = __float_as_uint(f);
  u += 0x7fff + ((u >> 16) & 1);   // round-to-nearest-even (finite inputs)
  return (unsigned short)(u >> 16);
}

__device__ __forceinline__ void pack8(unsigned short* d, float4 v0, float4 v1) {
  d[0] = f2bf(v0.x); d[1] = f2bf(v0.y); d[2] = f2bf(v0.z); d[3] = f2bf(v0.w);
  d[4] = f2bf(v1.x); d[5] = f2bf(v1.y); d[6] = f2bf(v1.z); d[7] = f2bf(v1.w);
}

__device__ __forceinline__ float fast_tanh(float x) {
  float e = __expf(2.0f * x);
  return 1.0f - 2.0f / (e + 1.0f);
}

// ---------------- Phase 0: fp32 -> bf16 pre-pass ----------------
__global__ __launch_bounds__(256) void cvt_kernel(
    const float* __restrict__ x, const float* __restrict__ Wx,
    unsigned short* __restrict__ xb, unsigned short* __restrict__ wxb) {
  const long long NX = (long long)Bsz * Tsz * Hsz / 8;   // 4,194,304 chunks
  const long long NW = (long long)Hsz * Hsz / 8;         //   131,072 chunks
  const long long stride = (long long)gridDim.x * 256;
  for (long long i = (long long)blockIdx.x * 256 + threadIdx.x;
       i < NX + NW; i += stride) {
    const float* s; unsigned short* d; long long j;
    if (i < NX) { s = x;  d = xb;  j = i; }
    else        { s = Wx; d = wxb; j = i - NX; }
    const float4 a = *(const float4*)(s + j * 8);
    const float4 b = *(const float4*)(s + j * 8 + 4);
    unsigned short tmp[8];
    pack8(tmp, a, b);
    *(s16x8*)(d + j * 8) = *(const s16x8*)tmp;
  }
}

// ---------------- Phase 1a: xp GEMM, bf16 sources (fast path) -------------
__global__ __launch_bounds__(256) void xp_gemm_bf16_kernel(
    const unsigned short* __restrict__ xb, const unsigned short* __restrict__ wxb,
    const float* __restrict__ bx, const float* __restrict__ bh,
    float* __restrict__ xp) {
  __shared__ unsigned short Al[64 * 32];
  __shared__ unsigned short Bl[64 * 32];

  const int tid  = threadIdx.x;
  const int w    = tid >> 6;
  const int lane = tid & 63;
  const int m    = lane & 15;
  const int q    = lane >> 4;
  const int row0 = blockIdx.x * 64;   // flattened (b*T + t) row base
  const int col0 = blockIdx.y * 64;   // hidden col base

  f32x4 acc[4];
#pragma unroll
  for (int i = 0; i < 4; ++i) acc[i] = (f32x4){0.f, 0.f, 0.f, 0.f};

  const int sr = tid >> 2;
  const int sc = tid & 3;
  const int sw = sc ^ ((sr >> 1) & 3);

  for (int kt = 0; kt < 32; ++kt) {
    const int k0 = kt * 32 + sc * 8;
    *(s16x8*)&Al[sr * 32 + sw * 8] =
        *(const s16x8*)(xb + (size_t)(row0 + sr) * 1024 + k0);
    *(s16x8*)&Bl[sr * 32 + sw * 8] =
        *(const s16x8*)(wxb + (size_t)(col0 + sr) * 1024 + k0);
    __syncthreads();
    const int arow = w * 16 + m;
    s16x8 a = *(const s16x8*)&Al[arow * 32 + ((q ^ ((arow >> 1) & 3)) << 3)];
#pragma unroll
    for (int nt = 0; nt < 4; ++nt) {
      const int nrow = nt * 16 + m;
      s16x8 b = *(const s16x8*)&Bl[nrow * 32 + ((q ^ ((nrow >> 1) & 3)) << 3)];
      acc[nt] = __builtin_amdgcn_mfma_f32_16x16x32_bf16(a, b, acc[nt], 0, 0, 0);
    }
    __syncthreads();
  }

#pragma unroll
  for (int nt = 0; nt < 4; ++nt) {
    const int col  = col0 + nt * 16 + m;
    const float bias = bx[col] + bh[col];
#pragma unroll
    for (int r = 0; r < 4; ++r) {
      const int rowg = row0 + w * 16 + q * 4 + r;  // = b*512 + t
      const int b = rowg >> 9;
      const int t = rowg & 511;
      xp[(size_t)t * (Bsz * Hsz) + b * Hsz + col] = acc[nt][r] + bias;
    }
  }
}

// ---------------- Phase 1b: original fp32-staging GEMM (fallback) ---------
__global__ __launch_bounds__(256) void xp_gemm_f32_kernel(
    const float* __restrict__ x, const float* __restrict__ Wx,
    const float* __restrict__ bx, const float* __restrict__ bh,
    float* __restrict__ xp) {
  __shared__ unsigned short Al[64 * 32];
  __shared__ unsigned short Bl[64 * 32];

  const int tid  = threadIdx.x;
  const int w    = tid >> 6;
  const int lane = tid & 63;
  const int m    = lane & 15;
  const int q    = lane >> 4;
  const int row0 = blockIdx.x * 64;
  const int col0 = blockIdx.y * 64;

  f32x4 acc[4];
#pragma unroll
  for (int i = 0; i < 4; ++i) acc[i] = (f32x4){0.f, 0.f, 0.f, 0.f};

  const int sr = tid >> 2;
  const int sc = tid & 3;
  const int sw = sc ^ ((sr >> 1) & 3);

  for (int kt = 0; kt < 32; ++kt) {
    const int k0 = kt * 32 + sc * 8;
    {
      const float* p = x + (size_t)(row0 + sr) * 1024 + k0;
      pack8(&Al[sr * 32 + sw * 8], *(const float4*)p, *(const float4*)(p + 4));
    }
    {
      const float* p = Wx + (size_t)(col0 + sr) * 1024 + k0;
      pack8(&Bl[sr * 32 + sw * 8], *(const float4*)p, *(const float4*)(p + 4));
    }
    __syncthreads();
    const int arow = w * 16 + m;
    s16x8 a = *(const s16x8*)&Al[arow * 32 + ((q ^ ((arow >> 1) & 3)) << 3)];
#pragma unroll
    for (int nt = 0; nt < 4; ++nt) {
      const int nrow = nt * 16 + m;
      s16x8 b = *(const s16x8*)&Bl[nrow * 32 + ((q ^ ((nrow >> 1) & 3)) << 3)];
      acc[nt] = __builtin_amdgcn_mfma_f32_16x16x32_bf16(a, b, acc[nt], 0, 0, 0);
    }
    __syncthreads();
  }

#pragma unroll
  for (int nt = 0; nt < 4; ++nt) {
    const int col  = col0 + nt * 16 + m;
    const float bias = bx[col] + bh[col];
#pragma unroll
    for (int r = 0; r < 4; ++r) {
      const int rowg = row0 + w * 16 + q * 4 + r;
      const int b = rowg >> 9;
      const int t = rowg & 511;
      xp[(size_t)t * (Bsz * Hsz) + b * Hsz + col] = acc[nt][r] + bias;
    }
  }
}

// ---------------- Phase 2: flag-gated C^T scan (R6, packed flags) ---------
// Ring (bf16 units): slot[2] x group[4] x [(k>>3)*128 + b*8 + (k&7)],
// k = hidden 0..1023, b = batch-local 0..15.
// Slot stride 16384 u64 (128 KB), group stride 4096 u64 (32 KB).
// Consumer frag kk, lane(m,q): u64 idx = kk*128 + q*32 + m*2 (+1).
// Producer wave gj, lane(m,q): u64 idx = (gj*2+(q>>1))*32 + m*2 + (q&1),
// hv[0..3] packed low->high.   [R6-validated]
// Flags: u32 per producer, STRIDE 1 (64 flags = 4 cache lines per group).

__global__ __launch_bounds__(64, 1) void rnn_scan_kernel(
    const float* __restrict__ Wh, const float* __restrict__ xp,
    float* __restrict__ out,
    unsigned long long* __restrict__ ring, unsigned* __restrict__ flags) {
  __shared__ unsigned short Wl[16 * 1024];  // 32 KB: W rows j0..j0+15, bf16

  const int lane = threadIdx.x & 63;
  const int m    = lane & 15;       // batch-local (B-frag col / C col)
  const int q    = lane >> 4;
  const int gb   = blockIdx.x >> 6; // 0..3  batch group
  const int gj   = blockIdx.x & 63; // 0..63 j-wave (16 output cols each)
  const int j0   = gj * 16;
  const int rb   = gb * 16;

  // W_h rows j0..j0+15 -> LDS bf16, chunk-swizzled (c ^= row&7); validated.
  for (int i = 0; i < 32; ++i) {
    const int jr = i >> 1;
    const int c  = (i & 1) * 64 + lane;     // 16-B chunk index 0..127
    const float* p = Wh + (size_t)(j0 + jr) * 1024 + c * 8;
    pack8(&Wl[jr * 1024 + ((c ^ (jr & 7)) << 3)],
          *(const float4*)p, *(const float4*)(p + 4));
  }
  __syncthreads();

  unsigned* grpflags = flags + gb * 64;            // 64 flags, stride 1
  unsigned* myflag   = grpflags + gj;
  const unsigned* pollflag = grpflags + lane;      // lane l polls producer l

  unsigned long long* const grp = ring + (size_t)gb * 4096;
  const int cons_off = q * 32 + m * 2;
  const int prod_off = (gj * 2 + (q >> 1)) * 32 + m * 2 + (q & 1);

  for (int t = 0; t < Tsz; ++t) {
    // xp_t for (b = rb+m, j = j0+q*4+r) — independent of recurrence
    const float4 xv = *(const float4*)(
        xp + (size_t)t * (Bsz * Hsz) + (size_t)(rb + m) * Hsz + j0 + q * 4);
    const float* xf = (const float*)&xv;

    f32x4 acc0 = (f32x4){0.f, 0.f, 0.f, 0.f};
    f32x4 acc1 = (f32x4){0.f, 0.f, 0.f, 0.f};
    f32x4 acc2 = (f32x4){0.f, 0.f, 0.f, 0.f};
    f32x4 acc3 = (f32x4){0.f, 0.f, 0.f, 0.f};

    if (t > 0) {
      const unsigned tg = (unsigned)t;
      // Poll to full readiness: one flag per lane, wave-wide ballot.
      unsigned v = __hip_atomic_load(pollflag, __ATOMIC_RELAXED,
                                     __HIP_MEMORY_SCOPE_AGENT);
      while (!__all((int)(v >= tg))) {
        __builtin_amdgcn_s_sleep(1);
        v = __hip_atomic_load(pollflag, __ATOMIC_RELAXED,
                              __HIP_MEMORY_SCOPE_AGENT);
      }

      // Bulk-issue all data loads (contiguous u64 pairs per fragment).
      const unsigned long long* rbase =
          grp + (size_t)(t & 1) * 16384 + cons_off;
      unsigned long long d[64];
#pragma unroll
      for (int kk = 0; kk < 32; ++kk) {
        d[2 * kk]     = __hip_atomic_load(rbase + kk * 128,     __ATOMIC_RELAXED,
                                          __HIP_MEMORY_SCOPE_AGENT);
        d[2 * kk + 1] = __hip_atomic_load(rbase + kk * 128 + 1, __ATOMIC_RELAXED,
                                          __HIP_MEMORY_SCOPE_AGENT);
      }

#pragma unroll
      for (int kk = 0; kk < 32; ++kk) {
        union { unsigned long long u[2]; s16x8 v; } hb;
        hb.u[0] = d[2 * kk];
        hb.u[1] = d[2 * kk + 1];
        s16x8 wf = *(const s16x8*)&Wl[m * 1024 + (((kk * 4 + q) ^ (m & 7)) << 3)];
        f32x4& ac = ((kk & 3) == 0) ? acc0 : ((kk & 3) == 1) ? acc1
                   : ((kk & 3) == 2) ? acc2 : acc3;
        ac = __builtin_amdgcn_mfma_f32_16x16x32_bf16(wf, hb.v, ac, 0, 0, 0);
      }
    }

    const f32x4 accs = (acc0 + acc1) + (acc2 + acc3);
    float hv[4];
#pragma unroll
    for (int r = 0; r < 4; ++r) hv[r] = fast_tanh(accs[r] + xf[r]);

    if (t == Tsz - 1) {
      *(float4*)&out[(size_t)(rb + m) * Hsz + j0 + q * 4] =
          make_float4(hv[0], hv[1], hv[2], hv[3]);
    } else {
      const unsigned long long s =
          (unsigned long long)f2bf(hv[0])        |
          ((unsigned long long)f2bf(hv[1]) << 16) |
          ((unsigned long long)f2bf(hv[2]) << 32) |
          ((unsigned long long)f2bf(hv[3]) << 48);
      unsigned long long* wb =
          grp + (size_t)((t + 1) & 1) * 16384 + prod_off;
      __hip_atomic_store(wb, s, __ATOMIC_RELAXED, __HIP_MEMORY_SCOPE_AGENT);
      // Drain own store to the coherence point, then publish readiness.
      asm volatile("s_waitcnt vmcnt(0)" ::: "memory");
      if (lane == 0)
        __hip_atomic_store(myflag, (unsigned)(t + 1), __ATOMIC_RELAXED,
                           __HIP_MEMORY_SCOPE_AGENT);
    }
  }
}

extern "C" void kernel_launch(void* const* d_in, const int* in_sizes, int n_in,
                              void* d_out, int out_size, void* d_ws, size_t ws_size,
                              hipStream_t stream) {
  (void)in_sizes; (void)n_in; (void)out_size;
  const float* x  = (const float*)d_in[0];  // [64,512,1024]
  const float* Wh = (const float*)d_in[1];  // [1024,1024]
  const float* bh = (const float*)d_in[2];  // [1024]
  const float* Wx = (const float*)d_in[3];  // [1024,1024]
  const float* bx = (const float*)d_in[4];  // [1024]
  float* out = (float*)d_out;               // [64,1024]

  char* ws = (char*)d_ws;
  unsigned*           flags = (unsigned*)ws;                    // 1 KB used
  unsigned long long* ring  = (unsigned long long*)(ws + 65536);// 256 KB
  const size_t off_xp  = (size_t)1 << 20;
  const size_t off_xb  = off_xp + (size_t)Bsz * Tsz * Hsz * 4;  // +128 MB
  const size_t off_wxb = off_xb + (size_t)Bsz * Tsz * Hsz * 2;  // +64 MB
  const size_t need    = off_wxb + (size_t)Hsz * Hsz * 2;       // ~195 MB
  float*          xp  = (float*)(ws + off_xp);
  unsigned short* xb  = (unsigned short*)(ws + off_xb);
  unsigned short* wxb = (unsigned short*)(ws + off_wxb);

  // only flags need zeroing (step 0 reads no h buffer)
  hipMemsetAsync(d_ws, 0, 16384, stream);

  dim3 g1(Bsz * Tsz / 64, Hsz / 64);
  if (ws_size >= need) {
    cvt_kernel<<<dim3(2048), dim3(256), 0, stream>>>(x, Wx, xb, wxb);
    xp_gemm_bf16_kernel<<<g1, dim3(256), 0, stream>>>(xb, wxb, bx, bh, xp);
  } else {
    xp_gemm_f32_kernel<<<g1, dim3(256), 0, stream>>>(x, Wx, bx, bh, xp);
  }
  rnn_scan_kernel<<<dim3(256), dim3(64), 0, stream>>>(Wh, xp, out, ring, flags);
}

// Round 9
// 1833.173 us; speedup vs baseline: 1.4218x; 1.2709x over previous
//
#include <hip/hip_runtime.h>
#include <cmath>

// CustomRNNCell: h_{t+1} = tanh(h_t @ W_h^T + b_h + x_t @ W_x^T + b_x)
// B=64, T=512, H=I=1024. Output: h_final [64,1024] fp32.
//
// R13 = bf16-prepass GEMM (R12, kept: gemm+cvt 293us vs 351us) +
//       R6-exact scan with ONE publish/poll change:
//   - publish: lane0 atomicAdd(+1) on a per-group arrival counter
//     (memory-side atomic, fire-and-forget after the proven
//     store->vmcnt(0) drain; no shared-line store traffic).
//   - poll: single word cnt >= 64*t (one line per iteration) instead of
//     R6's 64-line flag gather per iteration.
//   - R12 lesson applied: counters 256 B apart; no cross-block shared
//     stored lines anywhere else.
//   Ring layout, 2-slot parity, drain order: R6-validated, unchanged.

#define Bsz 64
#define Tsz 512
#define Hsz 1024

typedef float  f32x4 __attribute__((ext_vector_type(4)));
typedef short  s16x8 __attribute__((ext_vector_type(8)));

__device__ __forceinline__ unsigned short f2bf(float f) {
  unsigned u = __float_as_uint(f);
  u += 0x7fff + ((u >> 16) & 1);   // round-to-nearest-even (finite inputs)
  return (unsigned short)(u >> 16);
}

__device__ __forceinline__ void pack8(unsigned short* d, float4 v0, float4 v1) {
  d[0] = f2bf(v0.x); d[1] = f2bf(v0.y); d[2] = f2bf(v0.z); d[3] = f2bf(v0.w);
  d[4] = f2bf(v1.x); d[5] = f2bf(v1.y); d[6] = f2bf(v1.z); d[7] = f2bf(v1.w);
}

__device__ __forceinline__ float fast_tanh(float x) {
  float e = __expf(2.0f * x);
  return 1.0f - 2.0f / (e + 1.0f);
}

// ---------------- Phase 0: fp32 -> bf16 pre-pass (validated R12) ----------
__global__ __launch_bounds__(256) void cvt_kernel(
    const float* __restrict__ x, const float* __restrict__ Wx,
    unsigned short* __restrict__ xb, unsigned short* __restrict__ wxb) {
  const long long NX = (long long)Bsz * Tsz * Hsz / 8;
  const long long NW = (long long)Hsz * Hsz / 8;
  const long long stride = (long long)gridDim.x * 256;
  for (long long i = (long long)blockIdx.x * 256 + threadIdx.x;
       i < NX + NW; i += stride) {
    const float* s; unsigned short* d; long long j;
    if (i < NX) { s = x;  d = xb;  j = i; }
    else        { s = Wx; d = wxb; j = i - NX; }
    const float4 a = *(const float4*)(s + j * 8);
    const float4 b = *(const float4*)(s + j * 8 + 4);
    unsigned short tmp[8];
    pack8(tmp, a, b);
    *(s16x8*)(d + j * 8) = *(const s16x8*)tmp;
  }
}

// ---------------- Phase 1a: xp GEMM, bf16 sources (validated R12) ---------
__global__ __launch_bounds__(256) void xp_gemm_bf16_kernel(
    const unsigned short* __restrict__ xb, const unsigned short* __restrict__ wxb,
    const float* __restrict__ bx, const float* __restrict__ bh,
    float* __restrict__ xp) {
  __shared__ unsigned short Al[64 * 32];
  __shared__ unsigned short Bl[64 * 32];

  const int tid  = threadIdx.x;
  const int w    = tid >> 6;
  const int lane = tid & 63;
  const int m    = lane & 15;
  const int q    = lane >> 4;
  const int row0 = blockIdx.x * 64;   // flattened (b*T + t) row base
  const int col0 = blockIdx.y * 64;   // hidden col base

  f32x4 acc[4];
#pragma unroll
  for (int i = 0; i < 4; ++i) acc[i] = (f32x4){0.f, 0.f, 0.f, 0.f};

  const int sr = tid >> 2;
  const int sc = tid & 3;
  const int sw = sc ^ ((sr >> 1) & 3);

  for (int kt = 0; kt < 32; ++kt) {
    const int k0 = kt * 32 + sc * 8;
    *(s16x8*)&Al[sr * 32 + sw * 8] =
        *(const s16x8*)(xb + (size_t)(row0 + sr) * 1024 + k0);
    *(s16x8*)&Bl[sr * 32 + sw * 8] =
        *(const s16x8*)(wxb + (size_t)(col0 + sr) * 1024 + k0);
    __syncthreads();
    const int arow = w * 16 + m;
    s16x8 a = *(const s16x8*)&Al[arow * 32 + ((q ^ ((arow >> 1) & 3)) << 3)];
#pragma unroll
    for (int nt = 0; nt < 4; ++nt) {
      const int nrow = nt * 16 + m;
      s16x8 b = *(const s16x8*)&Bl[nrow * 32 + ((q ^ ((nrow >> 1) & 3)) << 3)];
      acc[nt] = __builtin_amdgcn_mfma_f32_16x16x32_bf16(a, b, acc[nt], 0, 0, 0);
    }
    __syncthreads();
  }

#pragma unroll
  for (int nt = 0; nt < 4; ++nt) {
    const int col  = col0 + nt * 16 + m;
    const float bias = bx[col] + bh[col];
#pragma unroll
    for (int r = 0; r < 4; ++r) {
      const int rowg = row0 + w * 16 + q * 4 + r;  // = b*512 + t
      const int b = rowg >> 9;
      const int t = rowg & 511;
      xp[(size_t)t * (Bsz * Hsz) + b * Hsz + col] = acc[nt][r] + bias;
    }
  }
}

// ---------------- Phase 1b: original fp32-staging GEMM (fallback) ---------
__global__ __launch_bounds__(256) void xp_gemm_f32_kernel(
    const float* __restrict__ x, const float* __restrict__ Wx,
    const float* __restrict__ bx, const float* __restrict__ bh,
    float* __restrict__ xp) {
  __shared__ unsigned short Al[64 * 32];
  __shared__ unsigned short Bl[64 * 32];

  const int tid  = threadIdx.x;
  const int w    = tid >> 6;
  const int lane = tid & 63;
  const int m    = lane & 15;
  const int q    = lane >> 4;
  const int row0 = blockIdx.x * 64;
  const int col0 = blockIdx.y * 64;

  f32x4 acc[4];
#pragma unroll
  for (int i = 0; i < 4; ++i) acc[i] = (f32x4){0.f, 0.f, 0.f, 0.f};

  const int sr = tid >> 2;
  const int sc = tid & 3;
  const int sw = sc ^ ((sr >> 1) & 3);

  for (int kt = 0; kt < 32; ++kt) {
    const int k0 = kt * 32 + sc * 8;
    {
      const float* p = x + (size_t)(row0 + sr) * 1024 + k0;
      pack8(&Al[sr * 32 + sw * 8], *(const float4*)p, *(const float4*)(p + 4));
    }
    {
      const float* p = Wx + (size_t)(col0 + sr) * 1024 + k0;
      pack8(&Bl[sr * 32 + sw * 8], *(const float4*)p, *(const float4*)(p + 4));
    }
    __syncthreads();
    const int arow = w * 16 + m;
    s16x8 a = *(const s16x8*)&Al[arow * 32 + ((q ^ ((arow >> 1) & 3)) << 3)];
#pragma unroll
    for (int nt = 0; nt < 4; ++nt) {
      const int nrow = nt * 16 + m;
      s16x8 b = *(const s16x8*)&Bl[nrow * 32 + ((q ^ ((nrow >> 1) & 3)) << 3)];
      acc[nt] = __builtin_amdgcn_mfma_f32_16x16x32_bf16(a, b, acc[nt], 0, 0, 0);
    }
    __syncthreads();
  }

#pragma unroll
  for (int nt = 0; nt < 4; ++nt) {
    const int col  = col0 + nt * 16 + m;
    const float bias = bx[col] + bh[col];
#pragma unroll
    for (int r = 0; r < 4; ++r) {
      const int rowg = row0 + w * 16 + q * 4 + r;
      const int b = rowg >> 9;
      const int t = rowg & 511;
      xp[(size_t)t * (Bsz * Hsz) + b * Hsz + col] = acc[nt][r] + bias;
    }
  }
}

// ---------------- Phase 2: R6 scan + arrival-counter publish/poll ---------
// Ring (bf16 units): slot[2] x group[4] x [(k>>3)*128 + b*8 + (k&7)],
// k = hidden 0..1023, b = batch-local 0..15.
// Slot stride 16384 u64 (128 KB), group stride 4096 u64 (32 KB).
// Consumer frag kk, lane(m,q): u64 idx = kk*128 + q*32 + m*2 (+1).
// Producer wave gj, lane(m,q): u64 idx = (gj*2+(q>>1))*32 + m*2 + (q&1),
// hv[0..3] packed low->high.   [R6-validated]
// Arrival: cnt[gb] (256-B apart). Producer: +1 after data drain. Consumer:
// wait cnt >= 64*t (monotone; all produced h_t). Ring safety as R6.

__global__ __launch_bounds__(64, 1) void rnn_scan_kernel(
    const float* __restrict__ Wh, const float* __restrict__ xp,
    float* __restrict__ out,
    unsigned long long* __restrict__ ring, unsigned* __restrict__ cnt) {
  __shared__ unsigned short Wl[16 * 1024];  // 32 KB: W rows j0..j0+15, bf16

  const int lane = threadIdx.x & 63;
  const int m    = lane & 15;       // batch-local (B-frag col / C col)
  const int q    = lane >> 4;
  const int gb   = blockIdx.x >> 6; // 0..3  batch group
  const int gj   = blockIdx.x & 63; // 0..63 j-wave (16 output cols each)
  const int j0   = gj * 16;
  const int rb   = gb * 16;

  // W_h rows j0..j0+15 -> LDS bf16, chunk-swizzled (c ^= row&7); validated.
  for (int i = 0; i < 32; ++i) {
    const int jr = i >> 1;
    const int c  = (i & 1) * 64 + lane;     // 16-B chunk index 0..127
    const float* p = Wh + (size_t)(j0 + jr) * 1024 + c * 8;
    pack8(&Wl[jr * 1024 + ((c ^ (jr & 7)) << 3)],
          *(const float4*)p, *(const float4*)(p + 4));
  }
  __syncthreads();

  unsigned* mycnt = cnt + gb * 64;   // one counter per group, 256 B apart

  unsigned long long* const grp = ring + (size_t)gb * 4096;
  const int cons_off = q * 32 + m * 2;
  const int prod_off = (gj * 2 + (q >> 1)) * 32 + m * 2 + (q & 1);

  for (int t = 0; t < Tsz; ++t) {
    // xp_t for (b = rb+m, j = j0+q*4+r) — independent of recurrence
    const float4 xv = *(const float4*)(
        xp + (size_t)t * (Bsz * Hsz) + (size_t)(rb + m) * Hsz + j0 + q * 4);
    const float* xf = (const float*)&xv;

    f32x4 acc0 = (f32x4){0.f, 0.f, 0.f, 0.f};
    f32x4 acc1 = (f32x4){0.f, 0.f, 0.f, 0.f};
    f32x4 acc2 = (f32x4){0.f, 0.f, 0.f, 0.f};
    f32x4 acc3 = (f32x4){0.f, 0.f, 0.f, 0.f};

    if (t > 0) {
      // Wait for all 64 producers of h_t: single-word poll (1 line).
      const unsigned target = (unsigned)(t << 6);
      unsigned v = __hip_atomic_load(mycnt, __ATOMIC_RELAXED,
                                     __HIP_MEMORY_SCOPE_AGENT);
      while (v < target) {
        __builtin_amdgcn_s_sleep(1);
        v = __hip_atomic_load(mycnt, __ATOMIC_RELAXED,
                              __HIP_MEMORY_SCOPE_AGENT);
      }

      // Bulk-issue all data loads (contiguous u64 pairs per fragment).
      const unsigned long long* rbase =
          grp + (size_t)(t & 1) * 16384 + cons_off;
      unsigned long long d[64];
#pragma unroll
      for (int kk = 0; kk < 32; ++kk) {
        d[2 * kk]     = __hip_atomic_load(rbase + kk * 128,     __ATOMIC_RELAXED,
                                          __HIP_MEMORY_SCOPE_AGENT);
        d[2 * kk + 1] = __hip_atomic_load(rbase + kk * 128 + 1, __ATOMIC_RELAXED,
                                          __HIP_MEMORY_SCOPE_AGENT);
      }

#pragma unroll
      for (int kk = 0; kk < 32; ++kk) {
        union { unsigned long long u[2]; s16x8 v; } hb;
        hb.u[0] = d[2 * kk];
        hb.u[1] = d[2 * kk + 1];
        s16x8 wf = *(const s16x8*)&Wl[m * 1024 + (((kk * 4 + q) ^ (m & 7)) << 3)];
        f32x4& ac = ((kk & 3) == 0) ? acc0 : ((kk & 3) == 1) ? acc1
                   : ((kk & 3) == 2) ? acc2 : acc3;
        ac = __builtin_amdgcn_mfma_f32_16x16x32_bf16(wf, hb.v, ac, 0, 0, 0);
      }
    }

    const f32x4 accs = (acc0 + acc1) + (acc2 + acc3);
    float hv[4];
#pragma unroll
    for (int r = 0; r < 4; ++r) hv[r] = fast_tanh(accs[r] + xf[r]);

    if (t == Tsz - 1) {
      *(float4*)&out[(size_t)(rb + m) * Hsz + j0 + q * 4] =
          make_float4(hv[0], hv[1], hv[2], hv[3]);
    } else {
      const unsigned long long s =
          (unsigned long long)f2bf(hv[0])        |
          ((unsigned long long)f2bf(hv[1]) << 16) |
          ((unsigned long long)f2bf(hv[2]) << 32) |
          ((unsigned long long)f2bf(hv[3]) << 48);
      unsigned long long* wb =
          grp + (size_t)((t + 1) & 1) * 16384 + prod_off;
      __hip_atomic_store(wb, s, __ATOMIC_RELAXED, __HIP_MEMORY_SCOPE_AGENT);
      // Drain own store to the coherence point, then publish arrival.
      asm volatile("s_waitcnt vmcnt(0)" ::: "memory");
      if (lane == 0)
        __hip_atomic_fetch_add(mycnt, 1u, __ATOMIC_RELAXED,
                               __HIP_MEMORY_SCOPE_AGENT);
    }
  }
}

extern "C" void kernel_launch(void* const* d_in, const int* in_sizes, int n_in,
                              void* d_out, int out_size, void* d_ws, size_t ws_size,
                              hipStream_t stream) {
  (void)in_sizes; (void)n_in; (void)out_size;
  const float* x  = (const float*)d_in[0];  // [64,512,1024]
  const float* Wh = (const float*)d_in[1];  // [1024,1024]
  const float* bh = (const float*)d_in[2];  // [1024]
  const float* Wx = (const float*)d_in[3];  // [1024,1024]
  const float* bx = (const float*)d_in[4];  // [1024]
  float* out = (float*)d_out;               // [64,1024]

  char* ws = (char*)d_ws;
  unsigned*           cnt  = (unsigned*)ws;                     // 1 KB used
  unsigned long long* ring = (unsigned long long*)(ws + 65536); // 256 KB
  const size_t off_xp  = (size_t)1 << 20;
  const size_t off_xb  = off_xp + (size_t)Bsz * Tsz * Hsz * 4;  // +128 MB
  const size_t off_wxb = off_xb + (size_t)Bsz * Tsz * Hsz * 2;  // +64 MB
  const size_t need    = off_wxb + (size_t)Hsz * Hsz * 2;       // ~195 MB
  float*          xp  = (float*)(ws + off_xp);
  unsigned short* xb  = (unsigned short*)(ws + off_xb);
  unsigned short* wxb = (unsigned short*)(ws + off_wxb);

  // zero counters (step 0 reads no h buffer)
  hipMemsetAsync(d_ws, 0, 16384, stream);

  dim3 g1(Bsz * Tsz / 64, Hsz / 64);
  if (ws_size >= need) {
    cvt_kernel<<<dim3(2048), dim3(256), 0, stream>>>(x, Wx, xb, wxb);
    xp_gemm_bf16_kernel<<<g1, dim3(256), 0, stream>>>(xb, wxb, bx, bh, xp);
  } else {
    xp_gemm_f32_kernel<<<g1, dim3(256), 0, stream>>>(x, Wx, bx, bh, xp);
  }
  rnn_scan_kernel<<<dim3(256), dim3(64), 0, stream>>>(Wh, xp, out, ring, cnt);
}

// Round 10
// 1668.827 us; speedup vs baseline: 1.5618x; 1.0985x over previous
//
#include <hip/hip_runtime.h>
#include <cmath>

// CustomRNNCell: h_{t+1} = tanh(h_t @ W_h^T + b_h + x_t @ W_x^T + b_x)
// B=64, T=512, H=I=1024. Output: h_final [64,1024] fp32.
//
// R14 = R6 scan VERBATIM (best of 9 protocol variants: 1410us) +
//       bf16 prepass (R12/R13, kept) + 128x128 GEMM tile:
//   - 64² tile = 275 TF (2-barrier structure ceiling). 128² tile with 2x2
//     waves x 4x4 fragments lifts MFMA:stage ratio 4x (ladder: 343->517 TF).
//   - Same validated LDS row layout (32 bf16/row) + XOR chunk swizzle +
//     fragment/epilogue index math as the 64² kernel; only the wave
//     quadrant decomposition and grid change. All acc indices static.

#define Bsz 64
#define Tsz 512
#define Hsz 1024

typedef float  f32x4 __attribute__((ext_vector_type(4)));
typedef short  s16x8 __attribute__((ext_vector_type(8)));

__device__ __forceinline__ unsigned short f2bf(float f) {
  unsigned u = __float_as_uint(f);
  u += 0x7fff + ((u >> 16) & 1);   // round-to-nearest-even (finite inputs)
  return (unsigned short)(u >> 16);
}

__device__ __forceinline__ void pack8(unsigned short* d, float4 v0, float4 v1) {
  d[0] = f2bf(v0.x); d[1] = f2bf(v0.y); d[2] = f2bf(v0.z); d[3] = f2bf(v0.w);
  d[4] = f2bf(v1.x); d[5] = f2bf(v1.y); d[6] = f2bf(v1.z); d[7] = f2bf(v1.w);
}

__device__ __forceinline__ float fast_tanh(float x) {
  float e = __expf(2.0f * x);
  return 1.0f - 2.0f / (e + 1.0f);
}

// ---------------- Phase 0: fp32 -> bf16 pre-pass (validated) ----------
__global__ __launch_bounds__(256) void cvt_kernel(
    const float* __restrict__ x, const float* __restrict__ Wx,
    unsigned short* __restrict__ xb, unsigned short* __restrict__ wxb) {
  const long long NX = (long long)Bsz * Tsz * Hsz / 8;
  const long long NW = (long long)Hsz * Hsz / 8;
  const long long stride = (long long)gridDim.x * 256;
  for (long long i = (long long)blockIdx.x * 256 + threadIdx.x;
       i < NX + NW; i += stride) {
    const float* s; unsigned short* d; long long j;
    if (i < NX) { s = x;  d = xb;  j = i; }
    else        { s = Wx; d = wxb; j = i - NX; }
    const float4 a = *(const float4*)(s + j * 8);
    const float4 b = *(const float4*)(s + j * 8 + 4);
    unsigned short tmp[8];
    pack8(tmp, a, b);
    *(s16x8*)(d + j * 8) = *(const s16x8*)tmp;
  }
}

// ---------------- Phase 1a: xp GEMM, 128x128 tile, bf16 sources -----------
__global__ __launch_bounds__(256) void xp_gemm128_kernel(
    const unsigned short* __restrict__ xb, const unsigned short* __restrict__ wxb,
    const float* __restrict__ bx, const float* __restrict__ bh,
    float* __restrict__ xp) {
  __shared__ unsigned short Al[128 * 32];   // 8 KB
  __shared__ unsigned short Bl[128 * 32];   // 8 KB

  const int tid  = threadIdx.x;
  const int w    = tid >> 6;
  const int lane = tid & 63;
  const int m    = lane & 15;
  const int q    = lane >> 4;
  const int wy   = w >> 1;            // 0..1 row quadrant
  const int wx   = w & 1;             // 0..1 col quadrant
  const int row0 = blockIdx.x * 128;  // flattened (b*T + t) row base
  const int col0 = blockIdx.y * 128;  // hidden col base

  f32x4 acc[4][4];
#pragma unroll
  for (int i = 0; i < 4; ++i)
#pragma unroll
    for (int j = 0; j < 4; ++j) acc[i][j] = (f32x4){0.f, 0.f, 0.f, 0.f};

  const int sr  = tid >> 1;           // staging row 0..127 (2 thr/row)
  const int sc  = tid & 1;            // which 16-elem half
  const int swz = (sr >> 1) & 3;

  for (int kt = 0; kt < 32; ++kt) {
    const int k0 = kt * 32 + sc * 16;
    {
      const unsigned short* p = xb + (size_t)(row0 + sr) * 1024 + k0;
      *(s16x8*)&Al[sr * 32 + (((sc * 2)     ^ swz) << 3)] = *(const s16x8*)p;
      *(s16x8*)&Al[sr * 32 + (((sc * 2 + 1) ^ swz) << 3)] = *(const s16x8*)(p + 8);
    }
    {
      const unsigned short* p = wxb + (size_t)(col0 + sr) * 1024 + k0;
      *(s16x8*)&Bl[sr * 32 + (((sc * 2)     ^ swz) << 3)] = *(const s16x8*)p;
      *(s16x8*)&Bl[sr * 32 + (((sc * 2 + 1) ^ swz) << 3)] = *(const s16x8*)(p + 8);
    }
    __syncthreads();

    s16x8 af[4], bf[4];
#pragma unroll
    for (int mt = 0; mt < 4; ++mt) {
      const int ar = wy * 64 + mt * 16 + m;
      af[mt] = *(const s16x8*)&Al[ar * 32 + ((q ^ ((ar >> 1) & 3)) << 3)];
    }
#pragma unroll
    for (int nt = 0; nt < 4; ++nt) {
      const int br = wx * 64 + nt * 16 + m;
      bf[nt] = *(const s16x8*)&Bl[br * 32 + ((q ^ ((br >> 1) & 3)) << 3)];
    }
#pragma unroll
    for (int mt = 0; mt < 4; ++mt)
#pragma unroll
      for (int nt = 0; nt < 4; ++nt)
        acc[mt][nt] = __builtin_amdgcn_mfma_f32_16x16x32_bf16(
            af[mt], bf[nt], acc[mt][nt], 0, 0, 0);
    __syncthreads();
  }

#pragma unroll
  for (int nt = 0; nt < 4; ++nt) {
    const int col  = col0 + wx * 64 + nt * 16 + m;
    const float bias = bx[col] + bh[col];
#pragma unroll
    for (int mt = 0; mt < 4; ++mt) {
#pragma unroll
      for (int r = 0; r < 4; ++r) {
        const int rowg = row0 + wy * 64 + mt * 16 + q * 4 + r;  // = b*512+t
        const int b = rowg >> 9;
        const int t = rowg & 511;
        xp[(size_t)t * (Bsz * Hsz) + b * Hsz + col] = acc[mt][nt][r] + bias;
      }
    }
  }
}

// ---------------- Phase 1b: original fp32-staging 64² GEMM (fallback) -----
__global__ __launch_bounds__(256) void xp_gemm_f32_kernel(
    const float* __restrict__ x, const float* __restrict__ Wx,
    const float* __restrict__ bx, const float* __restrict__ bh,
    float* __restrict__ xp) {
  __shared__ unsigned short Al[64 * 32];
  __shared__ unsigned short Bl[64 * 32];

  const int tid  = threadIdx.x;
  const int w    = tid >> 6;
  const int lane = tid & 63;
  const int m    = lane & 15;
  const int q    = lane >> 4;
  const int row0 = blockIdx.x * 64;
  const int col0 = blockIdx.y * 64;

  f32x4 acc[4];
#pragma unroll
  for (int i = 0; i < 4; ++i) acc[i] = (f32x4){0.f, 0.f, 0.f, 0.f};

  const int sr = tid >> 2;
  const int sc = tid & 3;
  const int sw = sc ^ ((sr >> 1) & 3);

  for (int kt = 0; kt < 32; ++kt) {
    const int k0 = kt * 32 + sc * 8;
    {
      const float* p = x + (size_t)(row0 + sr) * 1024 + k0;
      pack8(&Al[sr * 32 + sw * 8], *(const float4*)p, *(const float4*)(p + 4));
    }
    {
      const float* p = Wx + (size_t)(col0 + sr) * 1024 + k0;
      pack8(&Bl[sr * 32 + sw * 8], *(const float4*)p, *(const float4*)(p + 4));
    }
    __syncthreads();
    const int arow = w * 16 + m;
    s16x8 a = *(const s16x8*)&Al[arow * 32 + ((q ^ ((arow >> 1) & 3)) << 3)];
#pragma unroll
    for (int nt = 0; nt < 4; ++nt) {
      const int nrow = nt * 16 + m;
      s16x8 b = *(const s16x8*)&Bl[nrow * 32 + ((q ^ ((nrow >> 1) & 3)) << 3)];
      acc[nt] = __builtin_amdgcn_mfma_f32_16x16x32_bf16(a, b, acc[nt], 0, 0, 0);
    }
    __syncthreads();
  }

#pragma unroll
  for (int nt = 0; nt < 4; ++nt) {
    const int col  = col0 + nt * 16 + m;
    const float bias = bx[col] + bh[col];
#pragma unroll
    for (int r = 0; r < 4; ++r) {
      const int rowg = row0 + w * 16 + q * 4 + r;
      const int b = rowg >> 9;
      const int t = rowg & 511;
      xp[(size_t)t * (Bsz * Hsz) + b * Hsz + col] = acc[nt][r] + bias;
    }
  }
}

// ---------------- Phase 2: flag-gated C^T scan (R6 VERBATIM) ----------
// Ring (bf16 units): slot[2] x group[4] x [(k>>3)*128 + b*8 + (k&7)],
// k = hidden 0..1023, b = batch-local 0..15.
// Slot stride 16384 u64 (128 KB), group stride 4096 u64 (32 KB).
// Consumer frag kk, lane(m,q): u64 idx = kk*128 + q*32 + m*2 (+1).
// Producer wave gj, lane(m,q): u64 idx = (gj*2+(q>>1))*32 + m*2 + (q&1),
// hv[0..3] packed low->high.  Flags: 64-B stride (R12 lesson: packing
// flags into shared lines ping-pongs; keep one line per producer).

__global__ __launch_bounds__(64, 1) void rnn_scan_kernel(
    const float* __restrict__ Wh, const float* __restrict__ xp,
    float* __restrict__ out,
    unsigned long long* __restrict__ ring, unsigned* __restrict__ flags) {
  __shared__ unsigned short Wl[16 * 1024];  // 32 KB: W rows j0..j0+15, bf16

  const int lane = threadIdx.x & 63;
  const int m    = lane & 15;       // batch-local (B-frag col / C col)
  const int q    = lane >> 4;
  const int gb   = blockIdx.x >> 6; // 0..3  batch group
  const int gj   = blockIdx.x & 63; // 0..63 j-wave (16 output cols each)
  const int j0   = gj * 16;
  const int rb   = gb * 16;

  // W_h rows j0..j0+15 -> LDS bf16, chunk-swizzled (c ^= row&7); validated.
  for (int i = 0; i < 32; ++i) {
    const int jr = i >> 1;
    const int c  = (i & 1) * 64 + lane;     // 16-B chunk index 0..127
    const float* p = Wh + (size_t)(j0 + jr) * 1024 + c * 8;
    pack8(&Wl[jr * 1024 + ((c ^ (jr & 7)) << 3)],
          *(const float4*)p, *(const float4*)(p + 4));
  }
  __syncthreads();

  unsigned* grpflags = flags + gb * 1024;          // 64 flags x 64-B stride
  unsigned* myflag   = grpflags + gj * 16;
  const unsigned* pollflag = grpflags + lane * 16; // lane l polls producer l

  unsigned long long* const grp = ring + (size_t)gb * 4096;
  const int cons_off = q * 32 + m * 2;
  const int prod_off = (gj * 2 + (q >> 1)) * 32 + m * 2 + (q & 1);

  for (int t = 0; t < Tsz; ++t) {
    // xp_t for (b = rb+m, j = j0+q*4+r) — independent of recurrence
    const float4 xv = *(const float4*)(
        xp + (size_t)t * (Bsz * Hsz) + (size_t)(rb + m) * Hsz + j0 + q * 4);
    const float* xf = (const float*)&xv;

    f32x4 acc0 = (f32x4){0.f, 0.f, 0.f, 0.f};
    f32x4 acc1 = (f32x4){0.f, 0.f, 0.f, 0.f};
    f32x4 acc2 = (f32x4){0.f, 0.f, 0.f, 0.f};
    f32x4 acc3 = (f32x4){0.f, 0.f, 0.f, 0.f};

    if (t > 0) {
      const unsigned tg = (unsigned)t;
      // Poll to full readiness: one flag per lane, wave-wide ballot.
      unsigned v = __hip_atomic_load(pollflag, __ATOMIC_RELAXED,
                                     __HIP_MEMORY_SCOPE_AGENT);
      while (!__all((int)(v >= tg))) {
        __builtin_amdgcn_s_sleep(1);
        v = __hip_atomic_load(pollflag, __ATOMIC_RELAXED,
                              __HIP_MEMORY_SCOPE_AGENT);
      }

      // Bulk-issue all data loads (contiguous u64 pairs per fragment).
      const unsigned long long* rbase =
          grp + (size_t)(t & 1) * 16384 + cons_off;
      unsigned long long d[64];
#pragma unroll
      for (int kk = 0; kk < 32; ++kk) {
        d[2 * kk]     = __hip_atomic_load(rbase + kk * 128,     __ATOMIC_RELAXED,
                                          __HIP_MEMORY_SCOPE_AGENT);
        d[2 * kk + 1] = __hip_atomic_load(rbase + kk * 128 + 1, __ATOMIC_RELAXED,
                                          __HIP_MEMORY_SCOPE_AGENT);
      }

#pragma unroll
      for (int kk = 0; kk < 32; ++kk) {
        union { unsigned long long u[2]; s16x8 v; } hb;
        hb.u[0] = d[2 * kk];
        hb.u[1] = d[2 * kk + 1];
        s16x8 wf = *(const s16x8*)&Wl[m * 1024 + (((kk * 4 + q) ^ (m & 7)) << 3)];
        f32x4& ac = ((kk & 3) == 0) ? acc0 : ((kk & 3) == 1) ? acc1
                   : ((kk & 3) == 2) ? acc2 : acc3;
        ac = __builtin_amdgcn_mfma_f32_16x16x32_bf16(wf, hb.v, ac, 0, 0, 0);
      }
    }

    const f32x4 accs = (acc0 + acc1) + (acc2 + acc3);
    float hv[4];
#pragma unroll
    for (int r = 0; r < 4; ++r) hv[r] = fast_tanh(accs[r] + xf[r]);

    if (t == Tsz - 1) {
      *(float4*)&out[(size_t)(rb + m) * Hsz + j0 + q * 4] =
          make_float4(hv[0], hv[1], hv[2], hv[3]);
    } else {
      const unsigned long long s =
          (unsigned long long)f2bf(hv[0])        |
          ((unsigned long long)f2bf(hv[1]) << 16) |
          ((unsigned long long)f2bf(hv[2]) << 32) |
          ((unsigned long long)f2bf(hv[3]) << 48);
      unsigned long long* wb =
          grp + (size_t)((t + 1) & 1) * 16384 + prod_off;
      __hip_atomic_store(wb, s, __ATOMIC_RELAXED, __HIP_MEMORY_SCOPE_AGENT);
      // Drain own store to the coherence point, then publish readiness.
      asm volatile("s_waitcnt vmcnt(0)" ::: "memory");
      if (lane == 0)
        __hip_atomic_store(myflag, (unsigned)(t + 1), __ATOMIC_RELAXED,
                           __HIP_MEMORY_SCOPE_AGENT);
    }
  }
}

extern "C" void kernel_launch(void* const* d_in, const int* in_sizes, int n_in,
                              void* d_out, int out_size, void* d_ws, size_t ws_size,
                              hipStream_t stream) {
  (void)in_sizes; (void)n_in; (void)out_size;
  const float* x  = (const float*)d_in[0];  // [64,512,1024]
  const float* Wh = (const float*)d_in[1];  // [1024,1024]
  const float* bh = (const float*)d_in[2];  // [1024]
  const float* Wx = (const float*)d_in[3];  // [1024,1024]
  const float* bx = (const float*)d_in[4];  // [1024]
  float* out = (float*)d_out;               // [64,1024]

  char* ws = (char*)d_ws;
  unsigned*           flags = (unsigned*)ws;                    // 16 KB
  unsigned long long* ring  = (unsigned long long*)(ws + 65536);// 256 KB
  const size_t off_xp  = (size_t)1 << 20;
  const size_t off_xb  = off_xp + (size_t)Bsz * Tsz * Hsz * 4;  // +128 MB
  const size_t off_wxb = off_xb + (size_t)Bsz * Tsz * Hsz * 2;  // +64 MB
  const size_t need    = off_wxb + (size_t)Hsz * Hsz * 2;       // ~195 MB
  float*          xp  = (float*)(ws + off_xp);
  unsigned short* xb  = (unsigned short*)(ws + off_xb);
  unsigned short* wxb = (unsigned short*)(ws + off_wxb);

  // only flags need zeroing (step 0 reads no h buffer)
  hipMemsetAsync(d_ws, 0, 16384, stream);

  if (ws_size >= need) {
    cvt_kernel<<<dim3(2048), dim3(256), 0, stream>>>(x, Wx, xb, wxb);
    xp_gemm128_kernel<<<dim3(256, 8), dim3(256), 0, stream>>>(xb, wxb, bx, bh, xp);
  } else {
    dim3 g1(Bsz * Tsz / 64, Hsz / 64);
    xp_gemm_f32_kernel<<<g1, dim3(256), 0, stream>>>(x, Wx, bx, bh, xp);
  }
  rnn_scan_kernel<<<dim3(256), dim3(64), 0, stream>>>(Wh, xp, out, ring, flags);
}

// Round 11
// 1642.183 us; speedup vs baseline: 1.5871x; 1.0162x over previous
//
#include <hip/hip_runtime.h>
#include <cmath>

// CustomRNNCell: h_{t+1} = tanh(h_t @ W_h^T + b_h + x_t @ W_x^T + b_x)
// B=64, T=512, H=I=1024. Output: h_final [64,1024] fp32.
//
// R15 = R14 (1668us: R6 scan 1364 + cvt + 128² gemm) with ONE change:
//   gemm staging via __builtin_amdgcn_global_load_lds width=16 (ladder
//   step 3: 517->874 TF). XOR chunk swizzle preserved by pre-swizzling the
//   per-lane GLOBAL source address (LDS dest linear, wave-uniform base +
//   lane*16); fragment reads byte-identical to the validated R14 kernel.

#define Bsz 64
#define Tsz 512
#define Hsz 1024

typedef float  f32x4 __attribute__((ext_vector_type(4)));
typedef short  s16x8 __attribute__((ext_vector_type(8)));

#define AS1 __attribute__((address_space(1)))
#define AS3 __attribute__((address_space(3)))

__device__ __forceinline__ unsigned short f2bf(float f) {
  unsigned u = __float_as_uint(f);
  u += 0x7fff + ((u >> 16) & 1);   // round-to-nearest-even (finite inputs)
  return (unsigned short)(u >> 16);
}

__device__ __forceinline__ void pack8(unsigned short* d, float4 v0, float4 v1) {
  d[0] = f2bf(v0.x); d[1] = f2bf(v0.y); d[2] = f2bf(v0.z); d[3] = f2bf(v0.w);
  d[4] = f2bf(v1.x); d[5] = f2bf(v1.y); d[6] = f2bf(v1.z); d[7] = f2bf(v1.w);
}

__device__ __forceinline__ float fast_tanh(float x) {
  float e = __expf(2.0f * x);
  return 1.0f - 2.0f / (e + 1.0f);
}

// ---------------- Phase 0: fp32 -> bf16 pre-pass (validated) ----------
__global__ __launch_bounds__(256) void cvt_kernel(
    const float* __restrict__ x, const float* __restrict__ Wx,
    unsigned short* __restrict__ xb, unsigned short* __restrict__ wxb) {
  const long long NX = (long long)Bsz * Tsz * Hsz / 8;
  const long long NW = (long long)Hsz * Hsz / 8;
  const long long stride = (long long)gridDim.x * 256;
  for (long long i = (long long)blockIdx.x * 256 + threadIdx.x;
       i < NX + NW; i += stride) {
    const float* s; unsigned short* d; long long j;
    if (i < NX) { s = x;  d = xb;  j = i; }
    else        { s = Wx; d = wxb; j = i - NX; }
    const float4 a = *(const float4*)(s + j * 8);
    const float4 b = *(const float4*)(s + j * 8 + 4);
    unsigned short tmp[8];
    pack8(tmp, a, b);
    *(s16x8*)(d + j * 8) = *(const s16x8*)tmp;
  }
}

// ---------------- Phase 1a: xp GEMM, 128², global_load_lds staging --------
__global__ __launch_bounds__(256) void xp_gemm128_kernel(
    const unsigned short* __restrict__ xb, const unsigned short* __restrict__ wxb,
    const float* __restrict__ bx, const float* __restrict__ bh,
    float* __restrict__ xp) {
  __shared__ __align__(16) unsigned short Al[128 * 32];   // 8 KB, linear
  __shared__ __align__(16) unsigned short Bl[128 * 32];   // 8 KB, linear

  const int tid  = threadIdx.x;
  const int w    = tid >> 6;
  const int lane = tid & 63;
  const int m    = lane & 15;
  const int q    = lane >> 4;
  const int wy   = w >> 1;            // 0..1 row quadrant
  const int wx   = w & 1;             // 0..1 col quadrant
  const int row0 = blockIdx.x * 128;  // flattened (b*T + t) row base
  const int col0 = blockIdx.y * 128;  // hidden col base

  f32x4 acc[4][4];
#pragma unroll
  for (int i = 0; i < 4; ++i)
#pragma unroll
    for (int j = 0; j < 4; ++j) acc[i][j] = (f32x4){0.f, 0.f, 0.f, 0.f};

  // staging geometry: instr (w,i) covers rows w*32+i*16 .. +15 (1 KB).
  // lane l -> row += l>>2, chunk l&3. Pre-swizzled source chunk:
  // LDS[row][ch] must hold global chunk ch ^ ((row>>1)&3)  (validated).
  const int lrow = lane >> 2;         // 0..15
  const int lch  = lane & 3;

  for (int kt = 0; kt < 32; ++kt) {
    const int kb = kt * 32;
#pragma unroll
    for (int i = 0; i < 2; ++i) {
      const int ra  = w * 32 + i * 16 + lrow;      // local row 0..127
      const int scs = lch ^ ((ra >> 1) & 3);       // swizzled src chunk
      const unsigned short* gA = xb  + (size_t)(row0 + ra) * 1024 + kb + scs * 8;
      const unsigned short* gB = wxb + (size_t)(col0 + ra) * 1024 + kb + scs * 8;
      __builtin_amdgcn_global_load_lds(
          (const AS1 void*)gA, (AS3 void*)&Al[(w * 32 + i * 16) * 32], 16, 0, 0);
      __builtin_amdgcn_global_load_lds(
          (const AS1 void*)gB, (AS3 void*)&Bl[(w * 32 + i * 16) * 32], 16, 0, 0);
    }
    __syncthreads();   // drains vmcnt -> LDS tiles complete

    s16x8 af[4], bf[4];
#pragma unroll
    for (int mt = 0; mt < 4; ++mt) {
      const int ar = wy * 64 + mt * 16 + m;
      af[mt] = *(const s16x8*)&Al[ar * 32 + ((q ^ ((ar >> 1) & 3)) << 3)];
    }
#pragma unroll
    for (int nt = 0; nt < 4; ++nt) {
      const int br = wx * 64 + nt * 16 + m;
      bf[nt] = *(const s16x8*)&Bl[br * 32 + ((q ^ ((br >> 1) & 3)) << 3)];
    }
#pragma unroll
    for (int mt = 0; mt < 4; ++mt)
#pragma unroll
      for (int nt = 0; nt < 4; ++nt)
        acc[mt][nt] = __builtin_amdgcn_mfma_f32_16x16x32_bf16(
            af[mt], bf[nt], acc[mt][nt], 0, 0, 0);
    __syncthreads();
  }

#pragma unroll
  for (int nt = 0; nt < 4; ++nt) {
    const int col  = col0 + wx * 64 + nt * 16 + m;
    const float bias = bx[col] + bh[col];
#pragma unroll
    for (int mt = 0; mt < 4; ++mt) {
#pragma unroll
      for (int r = 0; r < 4; ++r) {
        const int rowg = row0 + wy * 64 + mt * 16 + q * 4 + r;  // = b*512+t
        const int b = rowg >> 9;
        const int t = rowg & 511;
        xp[(size_t)t * (Bsz * Hsz) + b * Hsz + col] = acc[mt][nt][r] + bias;
      }
    }
  }
}

// ---------------- Phase 1b: original fp32-staging 64² GEMM (fallback) -----
__global__ __launch_bounds__(256) void xp_gemm_f32_kernel(
    const float* __restrict__ x, const float* __restrict__ Wx,
    const float* __restrict__ bx, const float* __restrict__ bh,
    float* __restrict__ xp) {
  __shared__ unsigned short Al[64 * 32];
  __shared__ unsigned short Bl[64 * 32];

  const int tid  = threadIdx.x;
  const int w    = tid >> 6;
  const int lane = tid & 63;
  const int m    = lane & 15;
  const int q    = lane >> 4;
  const int row0 = blockIdx.x * 64;
  const int col0 = blockIdx.y * 64;

  f32x4 acc[4];
#pragma unroll
  for (int i = 0; i < 4; ++i) acc[i] = (f32x4){0.f, 0.f, 0.f, 0.f};

  const int sr = tid >> 2;
  const int sc = tid & 3;
  const int sw = sc ^ ((sr >> 1) & 3);

  for (int kt = 0; kt < 32; ++kt) {
    const int k0 = kt * 32 + sc * 8;
    {
      const float* p = x + (size_t)(row0 + sr) * 1024 + k0;
      pack8(&Al[sr * 32 + sw * 8], *(const float4*)p, *(const float4*)(p + 4));
    }
    {
      const float* p = Wx + (size_t)(col0 + sr) * 1024 + k0;
      pack8(&Bl[sr * 32 + sw * 8], *(const float4*)p, *(const float4*)(p + 4));
    }
    __syncthreads();
    const int arow = w * 16 + m;
    s16x8 a = *(const s16x8*)&Al[arow * 32 + ((q ^ ((arow >> 1) & 3)) << 3)];
#pragma unroll
    for (int nt = 0; nt < 4; ++nt) {
      const int nrow = nt * 16 + m;
      s16x8 b = *(const s16x8*)&Bl[nrow * 32 + ((q ^ ((nrow >> 1) & 3)) << 3)];
      acc[nt] = __builtin_amdgcn_mfma_f32_16x16x32_bf16(a, b, acc[nt], 0, 0, 0);
    }
    __syncthreads();
  }

#pragma unroll
  for (int nt = 0; nt < 4; ++nt) {
    const int col  = col0 + nt * 16 + m;
    const float bias = bx[col] + bh[col];
#pragma unroll
    for (int r = 0; r < 4; ++r) {
      const int rowg = row0 + w * 16 + q * 4 + r;
      const int b = rowg >> 9;
      const int t = rowg & 511;
      xp[(size_t)t * (Bsz * Hsz) + b * Hsz + col] = acc[nt][r] + bias;
    }
  }
}

// ---------------- Phase 2: flag-gated C^T scan (R6 VERBATIM) ----------
// Ring (bf16 units): slot[2] x group[4] x [(k>>3)*128 + b*8 + (k&7)],
// k = hidden 0..1023, b = batch-local 0..15.
// Slot stride 16384 u64 (128 KB), group stride 4096 u64 (32 KB).
// Consumer frag kk, lane(m,q): u64 idx = kk*128 + q*32 + m*2 (+1).
// Producer wave gj, lane(m,q): u64 idx = (gj*2+(q>>1))*32 + m*2 + (q&1),
// hv[0..3] packed low->high.  Flags: 64-B stride (R12 lesson: packed
// flag lines ping-pong; keep one line per producer).

__global__ __launch_bounds__(64, 1) void rnn_scan_kernel(
    const float* __restrict__ Wh, const float* __restrict__ xp,
    float* __restrict__ out,
    unsigned long long* __restrict__ ring, unsigned* __restrict__ flags) {
  __shared__ unsigned short Wl[16 * 1024];  // 32 KB: W rows j0..j0+15, bf16

  const int lane = threadIdx.x & 63;
  const int m    = lane & 15;       // batch-local (B-frag col / C col)
  const int q    = lane >> 4;
  const int gb   = blockIdx.x >> 6; // 0..3  batch group
  const int gj   = blockIdx.x & 63; // 0..63 j-wave (16 output cols each)
  const int j0   = gj * 16;
  const int rb   = gb * 16;

  // W_h rows j0..j0+15 -> LDS bf16, chunk-swizzled (c ^= row&7); validated.
  for (int i = 0; i < 32; ++i) {
    const int jr = i >> 1;
    const int c  = (i & 1) * 64 + lane;     // 16-B chunk index 0..127
    const float* p = Wh + (size_t)(j0 + jr) * 1024 + c * 8;
    pack8(&Wl[jr * 1024 + ((c ^ (jr & 7)) << 3)],
          *(const float4*)p, *(const float4*)(p + 4));
  }
  __syncthreads();

  unsigned* grpflags = flags + gb * 1024;          // 64 flags x 64-B stride
  unsigned* myflag   = grpflags + gj * 16;
  const unsigned* pollflag = grpflags + lane * 16; // lane l polls producer l

  unsigned long long* const grp = ring + (size_t)gb * 4096;
  const int cons_off = q * 32 + m * 2;
  const int prod_off = (gj * 2 + (q >> 1)) * 32 + m * 2 + (q & 1);

  for (int t = 0; t < Tsz; ++t) {
    // xp_t for (b = rb+m, j = j0+q*4+r) — independent of recurrence
    const float4 xv = *(const float4*)(
        xp + (size_t)t * (Bsz * Hsz) + (size_t)(rb + m) * Hsz + j0 + q * 4);
    const float* xf = (const float*)&xv;

    f32x4 acc0 = (f32x4){0.f, 0.f, 0.f, 0.f};
    f32x4 acc1 = (f32x4){0.f, 0.f, 0.f, 0.f};
    f32x4 acc2 = (f32x4){0.f, 0.f, 0.f, 0.f};
    f32x4 acc3 = (f32x4){0.f, 0.f, 0.f, 0.f};

    if (t > 0) {
      const unsigned tg = (unsigned)t;
      // Poll to full readiness: one flag per lane, wave-wide ballot.
      unsigned v = __hip_atomic_load(pollflag, __ATOMIC_RELAXED,
                                     __HIP_MEMORY_SCOPE_AGENT);
      while (!__all((int)(v >= tg))) {
        __builtin_amdgcn_s_sleep(1);
        v = __hip_atomic_load(pollflag, __ATOMIC_RELAXED,
                              __HIP_MEMORY_SCOPE_AGENT);
      }

      // Bulk-issue all data loads (contiguous u64 pairs per fragment).
      const unsigned long long* rbase =
          grp + (size_t)(t & 1) * 16384 + cons_off;
      unsigned long long d[64];
#pragma unroll
      for (int kk = 0; kk < 32; ++kk) {
        d[2 * kk]     = __hip_atomic_load(rbase + kk * 128,     __ATOMIC_RELAXED,
                                          __HIP_MEMORY_SCOPE_AGENT);
        d[2 * kk + 1] = __hip_atomic_load(rbase + kk * 128 + 1, __ATOMIC_RELAXED,
                                          __HIP_MEMORY_SCOPE_AGENT);
      }

#pragma unroll
      for (int kk = 0; kk < 32; ++kk) {
        union { unsigned long long u[2]; s16x8 v; } hb;
        hb.u[0] = d[2 * kk];
        hb.u[1] = d[2 * kk + 1];
        s16x8 wf = *(const s16x8*)&Wl[m * 1024 + (((kk * 4 + q) ^ (m & 7)) << 3)];
        f32x4& ac = ((kk & 3) == 0) ? acc0 : ((kk & 3) == 1) ? acc1
                   : ((kk & 3) == 2) ? acc2 : acc3;
        ac = __builtin_amdgcn_mfma_f32_16x16x32_bf16(wf, hb.v, ac, 0, 0, 0);
      }
    }

    const f32x4 accs = (acc0 + acc1) + (acc2 + acc3);
    float hv[4];
#pragma unroll
    for (int r = 0; r < 4; ++r) hv[r] = fast_tanh(accs[r] + xf[r]);

    if (t == Tsz - 1) {
      *(float4*)&out[(size_t)(rb + m) * Hsz + j0 + q * 4] =
          make_float4(hv[0], hv[1], hv[2], hv[3]);
    } else {
      const unsigned long long s =
          (unsigned long long)f2bf(hv[0])        |
          ((unsigned long long)f2bf(hv[1]) << 16) |
          ((unsigned long long)f2bf(hv[2]) << 32) |
          ((unsigned long long)f2bf(hv[3]) << 48);
      unsigned long long* wb =
          grp + (size_t)((t + 1) & 1) * 16384 + prod_off;
      __hip_atomic_store(wb, s, __ATOMIC_RELAXED, __HIP_MEMORY_SCOPE_AGENT);
      // Drain own store to the coherence point, then publish readiness.
      asm volatile("s_waitcnt vmcnt(0)" ::: "memory");
      if (lane == 0)
        __hip_atomic_store(myflag, (unsigned)(t + 1), __ATOMIC_RELAXED,
                           __HIP_MEMORY_SCOPE_AGENT);
    }
  }
}

extern "C" void kernel_launch(void* const* d_in, const int* in_sizes, int n_in,
                              void* d_out, int out_size, void* d_ws, size_t ws_size,
                              hipStream_t stream) {
  (void)in_sizes; (void)n_in; (void)out_size;
  const float* x  = (const float*)d_in[0];  // [64,512,1024]
  const float* Wh = (const float*)d_in[1];  // [1024,1024]
  const float* bh = (const float*)d_in[2];  // [1024]
  const float* Wx = (const float*)d_in[3];  // [1024,1024]
  const float* bx = (const float*)d_in[4];  // [1024]
  float* out = (float*)d_out;               // [64,1024]

  char* ws = (char*)d_ws;
  unsigned*           flags = (unsigned*)ws;                    // 16 KB
  unsigned long long* ring  = (unsigned long long*)(ws + 65536);// 256 KB
  const size_t off_xp  = (size_t)1 << 20;
  const size_t off_xb  = off_xp + (size_t)Bsz * Tsz * Hsz * 4;  // +128 MB
  const size_t off_wxb = off_xb + (size_t)Bsz * Tsz * Hsz * 2;  // +64 MB
  const size_t need    = off_wxb + (size_t)Hsz * Hsz * 2;       // ~195 MB
  float*          xp  = (float*)(ws + off_xp);
  unsigned short* xb  = (unsigned short*)(ws + off_xb);
  unsigned short* wxb = (unsigned short*)(ws + off_wxb);

  // only flags need zeroing (step 0 reads no h buffer)
  hipMemsetAsync(d_ws, 0, 16384, stream);

  if (ws_size >= need) {
    cvt_kernel<<<dim3(2048), dim3(256), 0, stream>>>(x, Wx, xb, wxb);
    xp_gemm128_kernel<<<dim3(256, 8), dim3(256), 0, stream>>>(xb, wxb, bx, bh, xp);
  } else {
    dim3 g1(Bsz * Tsz / 64, Hsz / 64);
    xp_gemm_f32_kernel<<<g1, dim3(256), 0, stream>>>(x, Wx, bx, bh, xp);
  }
  rnn_scan_kernel<<<dim3(256), dim3(64), 0, stream>>>(Wh, xp, out, ring, flags);
}

// Round 12
// 1631.244 us; speedup vs baseline: 1.5978x; 1.0067x over previous
//
#include <hip/hip_runtime.h>
#include <cmath>

// CustomRNNCell: h_{t+1} = tanh(h_t @ W_h^T + b_h + x_t @ W_x^T + b_x)
// B=64, T=512, H=I=1024. Output: h_final [64,1024] fp32.
//
// R16 = R15 (1642us) with the gemm upgraded to the 2-phase double-buffered
// template (catalog T3-minimum):
//   - BK=64 (16 K-iters of 32 MFMA), LDS [2][128][64] bf16 = 64 KB.
//   - global_load_lds staging, 8-way XOR chunk swizzle. Since instr blocks
//     are 8-row aligned, src chunk = (lane&7)^(lane>>3) is constant/lane:
//     8 persistent pointers, +128 B/iter.
//   - Schedule: STAGE(next) -> compute(cur) -> barrier (drain lands after
//     MFMA covered the load latency) -> flip. One barrier per iter.
//   cvt + R6 scan + f32 fallback byte-identical to R15.

#define Bsz 64
#define Tsz 512
#define Hsz 1024

typedef float  f32x4 __attribute__((ext_vector_type(4)));
typedef short  s16x8 __attribute__((ext_vector_type(8)));

#define AS1 __attribute__((address_space(1)))
#define AS3 __attribute__((address_space(3)))

__device__ __forceinline__ unsigned short f2bf(float f) {
  unsigned u = __float_as_uint(f);
  u += 0x7fff + ((u >> 16) & 1);   // round-to-nearest-even (finite inputs)
  return (unsigned short)(u >> 16);
}

__device__ __forceinline__ void pack8(unsigned short* d, float4 v0, float4 v1) {
  d[0] = f2bf(v0.x); d[1] = f2bf(v0.y); d[2] = f2bf(v0.z); d[3] = f2bf(v0.w);
  d[4] = f2bf(v1.x); d[5] = f2bf(v1.y); d[6] = f2bf(v1.z); d[7] = f2bf(v1.w);
}

__device__ __forceinline__ float fast_tanh(float x) {
  float e = __expf(2.0f * x);
  return 1.0f - 2.0f / (e + 1.0f);
}

// ---------------- Phase 0: fp32 -> bf16 pre-pass (validated) ----------
__global__ __launch_bounds__(256) void cvt_kernel(
    const float* __restrict__ x, const float* __restrict__ Wx,
    unsigned short* __restrict__ xb, unsigned short* __restrict__ wxb) {
  const long long NX = (long long)Bsz * Tsz * Hsz / 8;
  const long long NW = (long long)Hsz * Hsz / 8;
  const long long stride = (long long)gridDim.x * 256;
  for (long long i = (long long)blockIdx.x * 256 + threadIdx.x;
       i < NX + NW; i += stride) {
    const float* s; unsigned short* d; long long j;
    if (i < NX) { s = x;  d = xb;  j = i; }
    else        { s = Wx; d = wxb; j = i - NX; }
    const float4 a = *(const float4*)(s + j * 8);
    const float4 b = *(const float4*)(s + j * 8 + 4);
    unsigned short tmp[8];
    pack8(tmp, a, b);
    *(s16x8*)(d + j * 8) = *(const s16x8*)tmp;
  }
}

// ---------------- Phase 1a: xp GEMM, 128², BK=64, 2-phase dbuf ------------
__global__ __launch_bounds__(256) void xp_gemm128_kernel(
    const unsigned short* __restrict__ xb, const unsigned short* __restrict__ wxb,
    const float* __restrict__ bx, const float* __restrict__ bh,
    float* __restrict__ xp) {
  __shared__ __align__(16) unsigned short Al[2][128 * 64];   // 2 x 16 KB
  __shared__ __align__(16) unsigned short Bl[2][128 * 64];   // 2 x 16 KB

  const int tid  = threadIdx.x;
  const int w    = tid >> 6;
  const int lane = tid & 63;
  const int m    = lane & 15;
  const int q    = lane >> 4;
  const int wy   = w >> 1;            // 0..1 row quadrant
  const int wx   = w & 1;             // 0..1 col quadrant
  const int row0 = blockIdx.x * 128;  // flattened (b*T + t) row base
  const int col0 = blockIdx.y * 128;  // hidden col base

  f32x4 acc[4][4];
#pragma unroll
  for (int i = 0; i < 4; ++i)
#pragma unroll
    for (int j = 0; j < 4; ++j) acc[i][j] = (f32x4){0.f, 0.f, 0.f, 0.f};

  // staging: instr (w,i) covers rows w*32+i*8 .. +7 (1 KB). lane l ->
  // row_local l>>3, chunk l&7. LDS[row][ch] must hold G-chunk ch^(row&7);
  // since row&7 == l>>3, src chunk = (l&7)^(l>>3): CONSTANT per lane.
  const int scs = (lane & 7) ^ (lane >> 3);
  const unsigned short* pA[4];
  const unsigned short* pB[4];
#pragma unroll
  for (int i = 0; i < 4; ++i) {
    const int ra = w * 32 + i * 8 + (lane >> 3);
    pA[i] = xb  + (size_t)(row0 + ra) * 1024 + scs * 8;
    pB[i] = wxb + (size_t)(col0 + ra) * 1024 + scs * 8;
  }

#define STAGE(BUF)                                                            \
  do {                                                                        \
    _Pragma("unroll")                                                         \
    for (int i_ = 0; i_ < 4; ++i_) {                                          \
      __builtin_amdgcn_global_load_lds((const AS1 void*)pA[i_],               \
          (AS3 void*)&Al[BUF][(w * 32 + i_ * 8) * 64], 16, 0, 0);             \
      __builtin_amdgcn_global_load_lds((const AS1 void*)pB[i_],               \
          (AS3 void*)&Bl[BUF][(w * 32 + i_ * 8) * 64], 16, 0, 0);             \
      pA[i_] += 64; pB[i_] += 64;                                             \
    }                                                                         \
  } while (0)

  // prologue: stage tile 0, wait, enter steady state
  STAGE(0);
  __syncthreads();

  int cur = 0;
  for (int kt = 0; kt < 16; ++kt) {
    if (kt < 15) STAGE(cur ^ 1);     // issue next tile's loads first

#pragma unroll
    for (int kk2 = 0; kk2 < 2; ++kk2) {
      s16x8 af[4], bf4[4];
#pragma unroll
      for (int mt = 0; mt < 4; ++mt) {
        const int ar = wy * 64 + mt * 16 + m;
        af[mt] = *(const s16x8*)
            &Al[cur][ar * 64 + (((kk2 * 4 + q) ^ (m & 7)) << 3)];
      }
#pragma unroll
      for (int nt = 0; nt < 4; ++nt) {
        const int br = wx * 64 + nt * 16 + m;
        bf4[nt] = *(const s16x8*)
            &Bl[cur][br * 64 + (((kk2 * 4 + q) ^ (m & 7)) << 3)];
      }
#pragma unroll
      for (int mt = 0; mt < 4; ++mt)
#pragma unroll
        for (int nt = 0; nt < 4; ++nt)
          acc[mt][nt] = __builtin_amdgcn_mfma_f32_16x16x32_bf16(
              af[mt], bf4[nt], acc[mt][nt], 0, 0, 0);
    }

    __syncthreads();   // drains vmcnt: next buffer complete; cur reusable
    cur ^= 1;
  }
#undef STAGE

#pragma unroll
  for (int nt = 0; nt < 4; ++nt) {
    const int col  = col0 + wx * 64 + nt * 16 + m;
    const float bias = bx[col] + bh[col];
#pragma unroll
    for (int mt = 0; mt < 4; ++mt) {
#pragma unroll
      for (int r = 0; r < 4; ++r) {
        const int rowg = row0 + wy * 64 + mt * 16 + q * 4 + r;  // = b*512+t
        const int b = rowg >> 9;
        const int t = rowg & 511;
        xp[(size_t)t * (Bsz * Hsz) + b * Hsz + col] = acc[mt][nt][r] + bias;
      }
    }
  }
}

// ---------------- Phase 1b: original fp32-staging 64² GEMM (fallback) -----
__global__ __launch_bounds__(256) void xp_gemm_f32_kernel(
    const float* __restrict__ x, const float* __restrict__ Wx,
    const float* __restrict__ bx, const float* __restrict__ bh,
    float* __restrict__ xp) {
  __shared__ unsigned short Al[64 * 32];
  __shared__ unsigned short Bl[64 * 32];

  const int tid  = threadIdx.x;
  const int w    = tid >> 6;
  const int lane = tid & 63;
  const int m    = lane & 15;
  const int q    = lane >> 4;
  const int row0 = blockIdx.x * 64;
  const int col0 = blockIdx.y * 64;

  f32x4 acc[4];
#pragma unroll
  for (int i = 0; i < 4; ++i) acc[i] = (f32x4){0.f, 0.f, 0.f, 0.f};

  const int sr = tid >> 2;
  const int sc = tid & 3;
  const int sw = sc ^ ((sr >> 1) & 3);

  for (int kt = 0; kt < 32; ++kt) {
    const int k0 = kt * 32 + sc * 8;
    {
      const float* p = x + (size_t)(row0 + sr) * 1024 + k0;
      pack8(&Al[sr * 32 + sw * 8], *(const float4*)p, *(const float4*)(p + 4));
    }
    {
      const float* p = Wx + (size_t)(col0 + sr) * 1024 + k0;
      pack8(&Bl[sr * 32 + sw * 8], *(const float4*)p, *(const float4*)(p + 4));
    }
    __syncthreads();
    const int arow = w * 16 + m;
    s16x8 a = *(const s16x8*)&Al[arow * 32 + ((q ^ ((arow >> 1) & 3)) << 3)];
#pragma unroll
    for (int nt = 0; nt < 4; ++nt) {
      const int nrow = nt * 16 + m;
      s16x8 b = *(const s16x8*)&Bl[nrow * 32 + ((q ^ ((nrow >> 1) & 3)) << 3)];
      acc[nt] = __builtin_amdgcn_mfma_f32_16x16x32_bf16(a, b, acc[nt], 0, 0, 0);
    }
    __syncthreads();
  }

#pragma unroll
  for (int nt = 0; nt < 4; ++nt) {
    const int col  = col0 + nt * 16 + m;
    const float bias = bx[col] + bh[col];
#pragma unroll
    for (int r = 0; r < 4; ++r) {
      const int rowg = row0 + w * 16 + q * 4 + r;
      const int b = rowg >> 9;
      const int t = rowg & 511;
      xp[(size_t)t * (Bsz * Hsz) + b * Hsz + col] = acc[nt][r] + bias;
    }
  }
}

// ---------------- Phase 2: flag-gated C^T scan (R6 VERBATIM) ----------
// Ring (bf16 units): slot[2] x group[4] x [(k>>3)*128 + b*8 + (k&7)],
// k = hidden 0..1023, b = batch-local 0..15.
// Slot stride 16384 u64 (128 KB), group stride 4096 u64 (32 KB).
// Consumer frag kk, lane(m,q): u64 idx = kk*128 + q*32 + m*2 (+1).
// Producer wave gj, lane(m,q): u64 idx = (gj*2+(q>>1))*32 + m*2 + (q&1),
// hv[0..3] packed low->high.  Flags: 64-B stride (R12 lesson: packed
// flag lines ping-pong; keep one line per producer).

__global__ __launch_bounds__(64, 1) void rnn_scan_kernel(
    const float* __restrict__ Wh, const float* __restrict__ xp,
    float* __restrict__ out,
    unsigned long long* __restrict__ ring, unsigned* __restrict__ flags) {
  __shared__ unsigned short Wl[16 * 1024];  // 32 KB: W rows j0..j0+15, bf16

  const int lane = threadIdx.x & 63;
  const int m    = lane & 15;       // batch-local (B-frag col / C col)
  const int q    = lane >> 4;
  const int gb   = blockIdx.x >> 6; // 0..3  batch group
  const int gj   = blockIdx.x & 63; // 0..63 j-wave (16 output cols each)
  const int j0   = gj * 16;
  const int rb   = gb * 16;

  // W_h rows j0..j0+15 -> LDS bf16, chunk-swizzled (c ^= row&7); validated.
  for (int i = 0; i < 32; ++i) {
    const int jr = i >> 1;
    const int c  = (i & 1) * 64 + lane;     // 16-B chunk index 0..127
    const float* p = Wh + (size_t)(j0 + jr) * 1024 + c * 8;
    pack8(&Wl[jr * 1024 + ((c ^ (jr & 7)) << 3)],
          *(const float4*)p, *(const float4*)(p + 4));
  }
  __syncthreads();

  unsigned* grpflags = flags + gb * 1024;          // 64 flags x 64-B stride
  unsigned* myflag   = grpflags + gj * 16;
  const unsigned* pollflag = grpflags + lane * 16; // lane l polls producer l

  unsigned long long* const grp = ring + (size_t)gb * 4096;
  const int cons_off = q * 32 + m * 2;
  const int prod_off = (gj * 2 + (q >> 1)) * 32 + m * 2 + (q & 1);

  for (int t = 0; t < Tsz; ++t) {
    // xp_t for (b = rb+m, j = j0+q*4+r) — independent of recurrence
    const float4 xv = *(const float4*)(
        xp + (size_t)t * (Bsz * Hsz) + (size_t)(rb + m) * Hsz + j0 + q * 4);
    const float* xf = (const float*)&xv;

    f32x4 acc0 = (f32x4){0.f, 0.f, 0.f, 0.f};
    f32x4 acc1 = (f32x4){0.f, 0.f, 0.f, 0.f};
    f32x4 acc2 = (f32x4){0.f, 0.f, 0.f, 0.f};
    f32x4 acc3 = (f32x4){0.f, 0.f, 0.f, 0.f};

    if (t > 0) {
      const unsigned tg = (unsigned)t;
      // Poll to full readiness: one flag per lane, wave-wide ballot.
      unsigned v = __hip_atomic_load(pollflag, __ATOMIC_RELAXED,
                                     __HIP_MEMORY_SCOPE_AGENT);
      while (!__all((int)(v >= tg))) {
        __builtin_amdgcn_s_sleep(1);
        v = __hip_atomic_load(pollflag, __ATOMIC_RELAXED,
                              __HIP_MEMORY_SCOPE_AGENT);
      }

      // Bulk-issue all data loads (contiguous u64 pairs per fragment).
      const unsigned long long* rbase =
          grp + (size_t)(t & 1) * 16384 + cons_off;
      unsigned long long d[64];
#pragma unroll
      for (int kk = 0; kk < 32; ++kk) {
        d[2 * kk]     = __hip_atomic_load(rbase + kk * 128,     __ATOMIC_RELAXED,
                                          __HIP_MEMORY_SCOPE_AGENT);
        d[2 * kk + 1] = __hip_atomic_load(rbase + kk * 128 + 1, __ATOMIC_RELAXED,
                                          __HIP_MEMORY_SCOPE_AGENT);
      }

#pragma unroll
      for (int kk = 0; kk < 32; ++kk) {
        union { unsigned long long u[2]; s16x8 v; } hb;
        hb.u[0] = d[2 * kk];
        hb.u[1] = d[2 * kk + 1];
        s16x8 wf = *(const s16x8*)&Wl[m * 1024 + (((kk * 4 + q) ^ (m & 7)) << 3)];
        f32x4& ac = ((kk & 3) == 0) ? acc0 : ((kk & 3) == 1) ? acc1
                   : ((kk & 3) == 2) ? acc2 : acc3;
        ac = __builtin_amdgcn_mfma_f32_16x16x32_bf16(wf, hb.v, ac, 0, 0, 0);
      }
    }

    const f32x4 accs = (acc0 + acc1) + (acc2 + acc3);
    float hv[4];
#pragma unroll
    for (int r = 0; r < 4; ++r) hv[r] = fast_tanh(accs[r] + xf[r]);

    if (t == Tsz - 1) {
      *(float4*)&out[(size_t)(rb + m) * Hsz + j0 + q * 4] =
          make_float4(hv[0], hv[1], hv[2], hv[3]);
    } else {
      const unsigned long long s =
          (unsigned long long)f2bf(hv[0])        |
          ((unsigned long long)f2bf(hv[1]) << 16) |
          ((unsigned long long)f2bf(hv[2]) << 32) |
          ((unsigned long long)f2bf(hv[3]) << 48);
      unsigned long long* wb =
          grp + (size_t)((t + 1) & 1) * 16384 + prod_off;
      __hip_atomic_store(wb, s, __ATOMIC_RELAXED, __HIP_MEMORY_SCOPE_AGENT);
      // Drain own store to the coherence point, then publish readiness.
      asm volatile("s_waitcnt vmcnt(0)" ::: "memory");
      if (lane == 0)
        __hip_atomic_store(myflag, (unsigned)(t + 1), __ATOMIC_RELAXED,
                           __HIP_MEMORY_SCOPE_AGENT);
    }
  }
}

extern "C" void kernel_launch(void* const* d_in, const int* in_sizes, int n_in,
                              void* d_out, int out_size, void* d_ws, size_t ws_size,
                              hipStream_t stream) {
  (void)in_sizes; (void)n_in; (void)out_size;
  const float* x  = (const float*)d_in[0];  // [64,512,1024]
  const float* Wh = (const float*)d_in[1];  // [1024,1024]
  const float* bh = (const float*)d_in[2];  // [1024]
  const float* Wx = (const float*)d_in[3];  // [1024,1024]
  const float* bx = (const float*)d_in[4];  // [1024]
  float* out = (float*)d_out;               // [64,1024]

  char* ws = (char*)d_ws;
  unsigned*           flags = (unsigned*)ws;                    // 16 KB
  unsigned long long* ring  = (unsigned long long*)(ws + 65536);// 256 KB
  const size_t off_xp  = (size_t)1 << 20;
  const size_t off_xb  = off_xp + (size_t)Bsz * Tsz * Hsz * 4;  // +128 MB
  const size_t off_wxb = off_xb + (size_t)Bsz * Tsz * Hsz * 2;  // +64 MB
  const size_t need    = off_wxb + (size_t)Hsz * Hsz * 2;       // ~195 MB
  float*          xp  = (float*)(ws + off_xp);
  unsigned short* xb  = (unsigned short*)(ws + off_xb);
  unsigned short* wxb = (unsigned short*)(ws + off_wxb);

  // only flags need zeroing (step 0 reads no h buffer)
  hipMemsetAsync(d_ws, 0, 16384, stream);

  if (ws_size >= need) {
    cvt_kernel<<<dim3(2048), dim3(256), 0, stream>>>(x, Wx, xb, wxb);
    xp_gemm128_kernel<<<dim3(256, 8), dim3(256), 0, stream>>>(xb, wxb, bx, bh, xp);
  } else {
    dim3 g1(Bsz * Tsz / 64, Hsz / 64);
    xp_gemm_f32_kernel<<<g1, dim3(256), 0, stream>>>(x, Wx, bx, bh, xp);
  }
  rnn_scan_kernel<<<dim3(256), dim3(64), 0, stream>>>(Wh, xp, out, ring, flags);
}